// Round 6
// baseline (513.731 us; speedup 1.0000x reference)
//
#include <hip/hip_runtime.h>
#include <stdint.h>

#define NN   8192
#define KDIM 3000
#define KP   3072          // K padded to multiple of 64 (zeros) -> guard-free GEMM
#define DDIM 512
#define LDIM 30
#define CAPJ 128           // max edges/row kept (binomial mean 33, sigma 5.7)
#define GEMM_BLOCKS 512    // 64 m-tiles x 8 n-tiles

typedef __attribute__((ext_vector_type(8))) short short8;   // 8 bf16 = 4 VGPR
typedef __attribute__((ext_vector_type(4))) float float4v;  // 4 f32 acc
typedef __attribute__((ext_vector_type(4))) float f4v;      // for nt loads

__device__ __forceinline__ float bf2f(unsigned short h) {
    union { unsigned int u; float f; } v; v.u = ((unsigned int)h) << 16; return v.f;
}
__device__ __forceinline__ unsigned short f2bf(float f) {
    union { float f; unsigned int u; } v; v.f = f;
    unsigned int r = v.u + 0x7FFF + ((v.u >> 16) & 1);   // RNE
    return (unsigned short)(r >> 16);
}
// async global->LDS, 16B per lane; LDS dest = wave-uniform base + lane*16
__device__ __forceinline__ void gl_lds16(const void* g, void* l) {
    __builtin_amdgcn_global_load_lds(
        (const __attribute__((address_space(1))) unsigned int*)g,
        (__attribute__((address_space(3))) unsigned int*)l, 16, 0, 0);
}

// ------------------------------------------------- prep (merged):
// blocks [0,NN):            A fp32 [NN][3000] -> bf16 [NN][3072] (pad zeros)
// blocks [NN, NN+1536):     W0 fp32 [3000][512] -> bf16 W0T [512][3072]
// block  NN+1536:           zero f0/f1 (ws is poisoned 0xAA)
__global__ __launch_bounds__(384) void k_prep(
    const float* __restrict__ A, unsigned short* __restrict__ Abf,
    const float* __restrict__ W0, unsigned short* __restrict__ W0T,
    float* __restrict__ f01) {
    int bid = blockIdx.x, t = threadIdx.x;
    if (bid < NN) {
        int k = t * 8;
        uint4 o = {0, 0, 0, 0};
        if (k < KDIM) {
            const float* src = A + (size_t)bid * KDIM + k;  // row base 12000B, 16-aligned
            f4v a = __builtin_nontemporal_load((const f4v*)src);      // read-once
            f4v b = __builtin_nontemporal_load((const f4v*)(src + 4));
            unsigned short* h = (unsigned short*)&o;
            h[0] = f2bf(a[0]); h[1] = f2bf(a[1]); h[2] = f2bf(a[2]); h[3] = f2bf(a[3]);
            h[4] = f2bf(b[0]); h[5] = f2bf(b[1]); h[6] = f2bf(b[2]); h[7] = f2bf(b[3]);
        }
        *(uint4*)(Abf + (size_t)bid * KP + k) = o;          // pad chunks -> zeros
    } else if (bid < NN + 1536) {
        __shared__ float tile[32][33];
        int b = bid - NN;
        int k0 = (b % 96) * 32, n0 = (b / 96) * 32;
        int tx = t & 31, ty = (t >> 5) & 7;                 // use threads 0..255
        if (t < 256) {
            #pragma unroll
            for (int p = 0; p < 4; p++) {
                int k = k0 + ty + p * 8;
                float val = 0.f;
                if (k < KDIM) val = W0[(size_t)k * DDIM + n0 + tx];
                tile[ty + p * 8][tx] = val;
            }
        }
        __syncthreads();
        if (t < 256) {
            #pragma unroll
            for (int p = 0; p < 4; p++) {
                int k = k0 + tx;                            // pad k -> 0
                int n = n0 + ty + p * 8;
                W0T[(size_t)n * KP + k] = f2bf(tile[tx][ty + p * 8]);
            }
        }
    } else {
        for (int idx = t; idx < 2 * NN / 4; idx += 384)
            ((uint4*)f01)[idx] = (uint4){0, 0, 0, 0};
    }
}

// ------------------------------------------------- mid kernel (heterogeneous):
// blocks [0,512):  GEMM Xbf = A*W0T^T + fused f0/f1 epilogue (MFMA-bound)
// blocks [512, 512+NN): graph-row scan -> compacted edge list (HBM-BW-bound)
// m114: MFMA waves and BW waves co-schedule to ~max, not sum.
#define BM 128
#define BN 64

__global__ __launch_bounds__(256) void k_mid(
    const unsigned short* __restrict__ A,    // [NN][KP] bf16, zero-padded
    const unsigned short* __restrict__ BT,   // [DDIM][KP] bf16, zero-padded
    const float* __restrict__ v0,
    const float* __restrict__ v1,
    unsigned short* __restrict__ Xbf,        // [NN][DDIM] bf16
    float* __restrict__ f0,
    float* __restrict__ f1,
    const float* __restrict__ G,             // [NN][NN] fp32 {0,1}
    int* __restrict__ jcnt,                  // [NN]
    int* __restrict__ jlist)                 // [NN][CAPJ]
{
    __shared__ __align__(16) unsigned short As[2][BM][32];  // 16 KB
    __shared__ __align__(16) unsigned short Bs[2][BN][32];  // 8 KB
    __shared__ int scnt;
    __shared__ int jbuf[CAPJ];
    int t = threadIdx.x, w = t >> 6, l = t & 63;
    int bid = blockIdx.x;

    if (bid >= GEMM_BLOCKS) {
        // ---------------- graph-row scan ----------------
        int r = bid - GEMM_BLOCKS;
        if (t == 0) scnt = 0;
        __syncthreads();
        const float* grow = G + (size_t)r * NN;
        #pragma unroll
        for (int it = 0; it < 8; it++) {
            int base = (it * 256 + t) * 4;
            f4v gv = __builtin_nontemporal_load((const f4v*)(grow + base));
            #pragma unroll
            for (int m = 0; m < 4; m++) {
                if (gv[m] != 0.f) {
                    int p = atomicAdd(&scnt, 1);
                    if (p < CAPJ) jbuf[p] = base + m;
                }
            }
        }
        __syncthreads();
        int n = scnt < CAPJ ? scnt : CAPJ;
        if (t == 0) jcnt[r] = n;
        if (t < n) jlist[(size_t)r * CAPJ + t] = jbuf[t];
        return;
    }

    // ---------------- GEMM ----------------
    int m0 = (bid >> 3) * BM, n0 = (bid & 7) * BN;
    int wm = (w & 1) * 64, wn = (w >> 1) * 32;

    float4v acc[4][2];
    #pragma unroll
    for (int mf = 0; mf < 4; mf++)
        #pragma unroll
        for (int nf = 0; nf < 2; nf++)
            acc[mf][nf] = (float4v){0.f, 0.f, 0.f, 0.f};

    int lr = l >> 2;            // lane row-in-issue  0..15
    int lk = (l & 3) * 8;       // lane k-in-half     0,8,16,24 (elements)
    const unsigned short* Abase = A  + (size_t)m0 * KP;
    const unsigned short* Bbase = BT + (size_t)n0 * KP;
    const int lA = l & 15;
    const int qA = (l >> 4) * 8;

    for (int k0 = 0; k0 < KP; k0 += 64) {
        if (k0) __syncthreads();                 // prev compute done, LDS reusable
        #pragma unroll
        for (int p = 0; p < 4; p++) {            // A: 16 issues of 1KB
            int q = w * 4 + p, h = q >> 3, rb = q & 7;
            gl_lds16(Abase + (size_t)(rb * 16 + lr) * KP + k0 + h * 32 + lk,
                     &As[h][rb * 16][0]);
        }
        #pragma unroll
        for (int p = 0; p < 2; p++) {            // B: 8 issues
            int q = w * 2 + p, h = q >> 2, rb = q & 3;
            gl_lds16(Bbase + (size_t)(rb * 16 + lr) * KP + k0 + h * 32 + lk,
                     &Bs[h][rb * 16][0]);
        }
        __syncthreads();                          // drain vmcnt + barrier

        #pragma unroll
        for (int h = 0; h < 2; h++) {
            short8 af[4], bfr[2];
            #pragma unroll
            for (int mf = 0; mf < 4; mf++)
                af[mf] = *(const short8*)&As[h][wm + mf * 16 + lA][qA];
            #pragma unroll
            for (int nf = 0; nf < 2; nf++)
                bfr[nf] = *(const short8*)&Bs[h][wn + nf * 16 + lA][qA];
            #pragma unroll
            for (int mf = 0; mf < 4; mf++)
                #pragma unroll
                for (int nf = 0; nf < 2; nf++)
                    acc[mf][nf] = __builtin_amdgcn_mfma_f32_16x16x32_bf16(
                        af[mf], bfr[nf], acc[mf][nf], 0, 0, 0);
        }
    }

    // epilogue. C/D layout: col=lane&15, row=(lane>>4)*4+r.
    int rq = (l >> 4) * 4;
    float vc0 = v0[n0 + wn + lA], vc1 = v0[n0 + wn + 16 + lA];
    float uc0 = v1[n0 + wn + lA], uc1 = v1[n0 + wn + 16 + lA];
    #pragma unroll
    for (int mf = 0; mf < 4; mf++) {
        #pragma unroll
        for (int nf = 0; nf < 2; nf++) {
            int col = n0 + wn + nf * 16 + lA;
            int row = m0 + wm + mf * 16 + rq;
            #pragma unroll
            for (int r = 0; r < 4; r++)
                Xbf[(size_t)(row + r) * DDIM + col] = f2bf(acc[mf][nf][r]);
        }
        #pragma unroll
        for (int r = 0; r < 4; r++) {            // f0/f1 row partials
            float s0 = acc[mf][0][r] * vc0 + acc[mf][1][r] * vc1;
            float s1 = acc[mf][0][r] * uc0 + acc[mf][1][r] * uc1;
            #pragma unroll
            for (int off = 8; off; off >>= 1) {
                s0 += __shfl_xor(s0, off);
                s1 += __shfl_xor(s1, off);
            }
            if (lA == 0) {
                int row = m0 + wm + mf * 16 + rq + r;
                atomicAdd(&f0[row], s0);
                atomicAdd(&f1[row], s1);
            }
        }
    }
}

// ------------------------------------------------- final: edge weights + gather
// scores bounded in (-0.5,0.5) -> softmax needs no max-subtraction:
// exp(w-m)/sum == exp(w)/sum exactly. Single-pass, then ELU, then row @ W1.
__global__ __launch_bounds__(256) void k_final(
    const int* __restrict__ jcnt,
    const int* __restrict__ jlist,
    const unsigned short* __restrict__ Xbf,  // [NN][DDIM] bf16
    const float* __restrict__ f0,
    const float* __restrict__ f1,
    const float* __restrict__ W1,            // [DDIM][LDIM] fp32
    float* __restrict__ out)                 // [NN][LDIM] fp32
{
    __shared__ int   jloc[CAPJ];
    __shared__ float elist[CAPJ];
    __shared__ float zrow[DDIM];
    __shared__ float red[256];
    int t = threadIdx.x;
    int i = blockIdx.x;

    int n = jcnt[i];
    float f0i = f0[i];
    if (t < n) {
        int j = jlist[(size_t)i * CAPJ + t];
        jloc[t] = j;
        float xe = f0i + f1[j];
        float sg = 1.0f / (1.0f + __expf(-xe));
        elist[t] = __expf(sg - 0.5f);
    }
    __syncthreads();

    float s = 0.f;
    for (int k = 0; k < n; k++) s += elist[k];     // LDS broadcast, ~33 iters
    float inv = 1.0f / fmaxf(s, 1e-30f);

    // thread owns dims 2t,2t+1: one dword of the bf16 row -> coalesced 1KB/row
    float a0 = 0.f, a1 = 0.f;
    int k = 0;
    for (; k + 4 <= n; k += 4) {
        int j0 = jloc[k], j1 = jloc[k+1], j2 = jloc[k+2], j3 = jloc[k+3];
        float e0 = elist[k], e1 = elist[k+1], e2 = elist[k+2], e3 = elist[k+3];
        unsigned int x0 = *(const unsigned int*)(Xbf + (size_t)j0 * DDIM + t * 2);
        unsigned int x1 = *(const unsigned int*)(Xbf + (size_t)j1 * DDIM + t * 2);
        unsigned int x2 = *(const unsigned int*)(Xbf + (size_t)j2 * DDIM + t * 2);
        unsigned int x3 = *(const unsigned int*)(Xbf + (size_t)j3 * DDIM + t * 2);
        a0 += e0 * bf2f((unsigned short)(x0 & 0xFFFFu))
            + e1 * bf2f((unsigned short)(x1 & 0xFFFFu))
            + e2 * bf2f((unsigned short)(x2 & 0xFFFFu))
            + e3 * bf2f((unsigned short)(x3 & 0xFFFFu));
        a1 += e0 * bf2f((unsigned short)(x0 >> 16))
            + e1 * bf2f((unsigned short)(x1 >> 16))
            + e2 * bf2f((unsigned short)(x2 >> 16))
            + e3 * bf2f((unsigned short)(x3 >> 16));
    }
    for (; k < n; k++) {
        int j = jloc[k];
        float e = elist[k];
        unsigned int xw = *(const unsigned int*)(Xbf + (size_t)j * DDIM + t * 2);
        a0 += e * bf2f((unsigned short)(xw & 0xFFFFu));
        a1 += e * bf2f((unsigned short)(xw >> 16));
    }
    a0 *= inv; a1 *= inv;
    zrow[2 * t]     = a0 > 0.f ? a0 : __expf(a0) - 1.0f;   // ELU
    zrow[2 * t + 1] = a1 > 0.f ? a1 : __expf(a1) - 1.0f;
    __syncthreads();

    // out[i,c] = sum_d zrow[d] * W1[d][c] ; 8 slabs x 32 lanes
    int c = t & 31, slab = t >> 5;
    float p = 0.f;
    if (c < LDIM) {
        #pragma unroll 4
        for (int q = 0; q < 64; q++) {
            int d = slab * 64 + q;
            p += zrow[d] * W1[d * LDIM + c];
        }
    }
    red[t] = p;
    __syncthreads();
    if (t < LDIM) {
        float sum = 0.f;
        #pragma unroll
        for (int s2 = 0; s2 < 8; s2++) sum += red[s2 * 32 + t];
        out[(size_t)i * LDIM + t] = sum;
    }
}

// ----------------------------------------------------------------
extern "C" void kernel_launch(void* const* d_in, const int* in_sizes, int n_in,
                              void* d_out, int out_size, void* d_ws, size_t ws_size,
                              hipStream_t stream) {
    (void)in_sizes; (void)n_in; (void)out_size; (void)ws_size;
    const float* nf = (const float*)d_in[0];   // [8192][3000]
    const float* G  = (const float*)d_in[1];   // [8192][8192]
    const float* W0 = (const float*)d_in[2];   // [3000][512]
    const float* v0 = (const float*)d_in[3];   // [512]
    const float* v1 = (const float*)d_in[4];   // [512]
    const float* W1 = (const float*)d_in[5];   // [512][30]
    float* out = (float*)d_out;                // [8192][30]

    char* ws = (char*)d_ws;
    size_t off = 0;
    unsigned short* Abf = (unsigned short*)(ws + off); off += (size_t)NN * KP * 2;    // 50,331,648
    unsigned short* W0T = (unsigned short*)(ws + off); off += (size_t)DDIM * KP * 2;  //  3,145,728
    unsigned short* Xbf = (unsigned short*)(ws + off); off += (size_t)NN * DDIM * 2;  //  8,388,608
    float* f0 = (float*)(ws + off); off += NN * 4;     // f0|f1 contiguous (zeroed together)
    float* f1 = (float*)(ws + off); off += NN * 4;
    int* jcnt  = (int*)(ws + off); off += NN * 4;
    int* jlist = (int*)(ws + off); off += (size_t)NN * CAPJ * 4;                      //  4,194,304

    hipLaunchKernelGGL(k_prep, dim3(NN + 1536 + 1), dim3(384), 0, stream,
                       nf, Abf, W0, W0T, f0);
    hipLaunchKernelGGL(k_mid, dim3(GEMM_BLOCKS + NN), dim3(256), 0, stream,
                       Abf, W0T, v0, v1, Xbf, f0, f1, G, jcnt, jlist);
    hipLaunchKernelGGL(k_final, dim3(NN), dim3(256), 0, stream,
                       jcnt, jlist, Xbf, f0, f1, W1, out);
}

// Round 7
// 507.699 us; speedup vs baseline: 1.0119x; 1.0119x over previous
//
#include <hip/hip_runtime.h>
#include <stdint.h>

#define NN   8192
#define KDIM 3000
#define KP   3072          // K padded to multiple of 64 (zeros) -> guard-free GEMM
#define DDIM 512
#define LDIM 30

typedef __attribute__((ext_vector_type(8))) short short8;   // 8 bf16 = 4 VGPR
typedef __attribute__((ext_vector_type(4))) float float4v;  // 4 f32 acc
typedef __attribute__((ext_vector_type(4))) float f4v;      // true vector type (nt loads)

__device__ __forceinline__ float bf2f(unsigned short h) {
    union { unsigned int u; float f; } v; v.u = ((unsigned int)h) << 16; return v.f;
}
__device__ __forceinline__ unsigned short f2bf(float f) {
    union { float f; unsigned int u; } v; v.f = f;
    unsigned int r = v.u + 0x7FFF + ((v.u >> 16) & 1);   // RNE
    return (unsigned short)(r >> 16);
}
// async global->LDS, 16B per lane; LDS dest = wave-uniform base + lane*16
__device__ __forceinline__ void gl_lds16(const void* g, void* l) {
    __builtin_amdgcn_global_load_lds(
        (const __attribute__((address_space(1))) unsigned int*)g,
        (__attribute__((address_space(3))) unsigned int*)l, 16, 0, 0);
}

// ------------------------------------------------- prep (merged):
// blocks [0,NN):            A fp32 [NN][3000] -> bf16 [NN][3072] (pad zeros)
// blocks [NN, NN+1536):     W0 fp32 [3000][512] -> bf16 W0T [512][3072]
// block  NN+1536:           zero f0/f1 (ws is poisoned 0xAA)
__global__ __launch_bounds__(384) void k_prep(
    const float* __restrict__ A, unsigned short* __restrict__ Abf,
    const float* __restrict__ W0, unsigned short* __restrict__ W0T,
    float* __restrict__ f01) {
    int bid = blockIdx.x, t = threadIdx.x;
    if (bid < NN) {
        int k = t * 8;
        uint4 o = {0, 0, 0, 0};
        if (k < KDIM) {
            const float* src = A + (size_t)bid * KDIM + k;  // row base 12000B, 16-aligned
            float4 a = *(const float4*)src;
            float4 b = *(const float4*)(src + 4);
            unsigned short* h = (unsigned short*)&o;
            h[0] = f2bf(a.x); h[1] = f2bf(a.y); h[2] = f2bf(a.z); h[3] = f2bf(a.w);
            h[4] = f2bf(b.x); h[5] = f2bf(b.y); h[6] = f2bf(b.z); h[7] = f2bf(b.w);
        }
        *(uint4*)(Abf + (size_t)bid * KP + k) = o;          // pad chunks -> zeros
    } else if (bid < NN + 1536) {
        __shared__ float tile[32][33];
        int b = bid - NN;
        int k0 = (b % 96) * 32, n0 = (b / 96) * 32;
        int tx = t & 31, ty = (t >> 5) & 7;                 // use threads 0..255
        if (t < 256) {
            #pragma unroll
            for (int p = 0; p < 4; p++) {
                int k = k0 + ty + p * 8;
                float val = 0.f;
                if (k < KDIM) val = W0[(size_t)k * DDIM + n0 + tx];
                tile[ty + p * 8][tx] = val;
            }
        }
        __syncthreads();
        if (t < 256) {
            #pragma unroll
            for (int p = 0; p < 4; p++) {
                int k = k0 + tx;                            // pad k -> 0
                int n = n0 + ty + p * 8;
                W0T[(size_t)n * KP + k] = f2bf(tile[tx][ty + p * 8]);
            }
        }
    } else {
        // zero f0|f1 : 2*NN floats = 4096 uint4
        for (int idx = t; idx < 2 * NN / 4; idx += 384)
            ((uint4*)f01)[idx] = (uint4){0, 0, 0, 0};
    }
}

// ------------------------------------------------- GEMM + fused f0/f1 epilogue
// X = A(bf16) * W0T^T -> Xbf (bf16); f0/f1 += per-tile row partials (atomic).
// BM=128, BN=64, BK=64 as two 32-halves (m97 structure, 16 MFMA/wave/iter).
// NOTE (R6 post-mortem): do NOT co-schedule the G-scan with this kernel —
// they share HBM BW and compose to ~sum, not ~max (tested: +4 us).
#define BM 128
#define BN 64

__global__ __launch_bounds__(256) void k_gemm(
    const unsigned short* __restrict__ A,    // [NN][KP] bf16, zero-padded
    const unsigned short* __restrict__ BT,   // [DDIM][KP] bf16, zero-padded
    const float* __restrict__ v0,
    const float* __restrict__ v1,
    unsigned short* __restrict__ Xbf,        // [NN][DDIM] bf16
    float* __restrict__ f0,
    float* __restrict__ f1)
{
    __shared__ __align__(16) unsigned short As[2][BM][32];  // 16 KB
    __shared__ __align__(16) unsigned short Bs[2][BN][32];  // 8 KB
    int t = threadIdx.x, w = t >> 6, l = t & 63;
    int m0 = blockIdx.x * BM, n0 = blockIdx.y * BN;
    int wm = (w & 1) * 64, wn = (w >> 1) * 32;

    float4v acc[4][2];
    #pragma unroll
    for (int mf = 0; mf < 4; mf++)
        #pragma unroll
        for (int nf = 0; nf < 2; nf++)
            acc[mf][nf] = (float4v){0.f, 0.f, 0.f, 0.f};

    int lr = l >> 2;            // lane row-in-issue  0..15
    int lk = (l & 3) * 8;       // lane k-in-half     0,8,16,24 (elements)
    const unsigned short* Abase = A  + (size_t)m0 * KP;
    const unsigned short* Bbase = BT + (size_t)n0 * KP;
    const int lA = l & 15;
    const int qA = (l >> 4) * 8;

    for (int k0 = 0; k0 < KP; k0 += 64) {
        if (k0) __syncthreads();                 // prev compute done, LDS reusable
        // A: 16 issues of 1KB (16 rows x 64B each); wave w takes q = w*4+p
        #pragma unroll
        for (int p = 0; p < 4; p++) {
            int q = w * 4 + p, h = q >> 3, rb = q & 7;
            gl_lds16(Abase + (size_t)(rb * 16 + lr) * KP + k0 + h * 32 + lk,
                     &As[h][rb * 16][0]);
        }
        // B: 8 issues; wave w takes q = w*2+p
        #pragma unroll
        for (int p = 0; p < 2; p++) {
            int q = w * 2 + p, h = q >> 2, rb = q & 3;
            gl_lds16(Bbase + (size_t)(rb * 16 + lr) * KP + k0 + h * 32 + lk,
                     &Bs[h][rb * 16][0]);
        }
        __syncthreads();                          // drain vmcnt + barrier

        #pragma unroll
        for (int h = 0; h < 2; h++) {
            short8 af[4], bfr[2];
            #pragma unroll
            for (int mf = 0; mf < 4; mf++)
                af[mf] = *(const short8*)&As[h][wm + mf * 16 + lA][qA];
            #pragma unroll
            for (int nf = 0; nf < 2; nf++)
                bfr[nf] = *(const short8*)&Bs[h][wn + nf * 16 + lA][qA];
            #pragma unroll
            for (int mf = 0; mf < 4; mf++)
                #pragma unroll
                for (int nf = 0; nf < 2; nf++)
                    acc[mf][nf] = __builtin_amdgcn_mfma_f32_16x16x32_bf16(
                        af[mf], bfr[nf], acc[mf][nf], 0, 0, 0);
        }
    }

    // ---- epilogue. C/D layout: col=lane&15, row=(lane>>4)*4+r.
    int rq = (l >> 4) * 4;
    float vc0 = v0[n0 + wn + lA], vc1 = v0[n0 + wn + 16 + lA];
    float uc0 = v1[n0 + wn + lA], uc1 = v1[n0 + wn + 16 + lA];
    #pragma unroll
    for (int mf = 0; mf < 4; mf++) {
        #pragma unroll
        for (int nf = 0; nf < 2; nf++) {
            int col = n0 + wn + nf * 16 + lA;
            int row = m0 + wm + mf * 16 + rq;
            #pragma unroll
            for (int r = 0; r < 4; r++)
                Xbf[(size_t)(row + r) * DDIM + col] = f2bf(acc[mf][nf][r]);
        }
        // f0/f1 partials: reduce 32 cols across the 16 lanes of this quad
        #pragma unroll
        for (int r = 0; r < 4; r++) {
            float s0 = acc[mf][0][r] * vc0 + acc[mf][1][r] * vc1;
            float s1 = acc[mf][0][r] * uc0 + acc[mf][1][r] * uc1;
            #pragma unroll
            for (int off = 8; off; off >>= 1) {
                s0 += __shfl_xor(s0, off);
                s1 += __shfl_xor(s1, off);
            }
            if (lA == 0) {
                int row = m0 + wm + mf * 16 + rq + r;
                atomicAdd(&f0[row], s0);
                atomicAdd(&f1[row], s1);
            }
        }
    }
}

// ------------------------------------------------- fused GAT row
// scores bounded in (-0.5,0.5) -> softmax needs no max-subtraction:
// exp(w-m)/sum == exp(w)/sum exactly. Single-pass weighted aggregation,
// scalar normalize, ELU, then row @ W1. G streamed with nt loads (read-once).
#define CAP 1024
__global__ __launch_bounds__(256) void k_aggregate(
    const float* __restrict__ G,             // [NN][NN] fp32 {0,1}
    const unsigned short* __restrict__ Xbf,  // [NN][DDIM] bf16
    const float* __restrict__ f0,
    const float* __restrict__ f1,
    const float* __restrict__ W1,            // [DDIM][LDIM] fp32
    float* __restrict__ out)                 // [NN][LDIM] fp32
{
    __shared__ int cnt;
    __shared__ int   jlist[CAP];
    __shared__ float elist[CAP];
    __shared__ float zrow[DDIM];
    __shared__ float red[256];
    int t = threadIdx.x;
    int i = blockIdx.x;
    if (t == 0) cnt = 0;
    __syncthreads();

    float f0i = f0[i];
    const float* grow = G + (size_t)i * NN;
    #pragma unroll
    for (int it = 0; it < 8; it++) {
        int base = (it * 256 + t) * 4;
        f4v gv = __builtin_nontemporal_load((const f4v*)(grow + base));
        #pragma unroll
        for (int m = 0; m < 4; m++) {
            if (gv[m] != 0.f) {
                int j = base + m;
                float xe = f0i + f1[j];
                float sg = 1.0f / (1.0f + __expf(-xe));
                float e  = __expf(sg - 0.5f);
                int p = atomicAdd(&cnt, 1);
                if (p < CAP) { jlist[p] = j; elist[p] = e; }
            }
        }
    }
    __syncthreads();

    int n = cnt < CAP ? cnt : CAP;
    float s = 0.f;
    for (int k = 0; k < n; k++) s += elist[k];     // LDS broadcast, ~33 iters
    float inv = 1.0f / fmaxf(s, 1e-30f);

    // thread owns dims 2t,2t+1: one dword of the bf16 row -> coalesced 1KB/row
    float a0 = 0.f, a1 = 0.f;
    int k = 0;
    for (; k + 4 <= n; k += 4) {
        int j0 = jlist[k], j1 = jlist[k+1], j2 = jlist[k+2], j3 = jlist[k+3];
        float e0 = elist[k], e1 = elist[k+1], e2 = elist[k+2], e3 = elist[k+3];
        unsigned int x0 = *(const unsigned int*)(Xbf + (size_t)j0 * DDIM + t * 2);
        unsigned int x1 = *(const unsigned int*)(Xbf + (size_t)j1 * DDIM + t * 2);
        unsigned int x2 = *(const unsigned int*)(Xbf + (size_t)j2 * DDIM + t * 2);
        unsigned int x3 = *(const unsigned int*)(Xbf + (size_t)j3 * DDIM + t * 2);
        a0 += e0 * bf2f((unsigned short)(x0 & 0xFFFFu))
            + e1 * bf2f((unsigned short)(x1 & 0xFFFFu))
            + e2 * bf2f((unsigned short)(x2 & 0xFFFFu))
            + e3 * bf2f((unsigned short)(x3 & 0xFFFFu));
        a1 += e0 * bf2f((unsigned short)(x0 >> 16))
            + e1 * bf2f((unsigned short)(x1 >> 16))
            + e2 * bf2f((unsigned short)(x2 >> 16))
            + e3 * bf2f((unsigned short)(x3 >> 16));
    }
    for (; k < n; k++) {
        int j = jlist[k];
        float e = elist[k];
        unsigned int xw = *(const unsigned int*)(Xbf + (size_t)j * DDIM + t * 2);
        a0 += e * bf2f((unsigned short)(xw & 0xFFFFu));
        a1 += e * bf2f((unsigned short)(xw >> 16));
    }
    a0 *= inv; a1 *= inv;
    zrow[2 * t]     = a0 > 0.f ? a0 : __expf(a0) - 1.0f;   // ELU
    zrow[2 * t + 1] = a1 > 0.f ? a1 : __expf(a1) - 1.0f;
    __syncthreads();

    // out[i,c] = sum_d zrow[d] * W1[d][c] ; 8 slabs x 32 lanes
    int c = t & 31, slab = t >> 5;
    float p = 0.f;
    if (c < LDIM) {
        #pragma unroll 4
        for (int q = 0; q < 64; q++) {
            int d = slab * 64 + q;
            p += zrow[d] * W1[d * LDIM + c];
        }
    }
    red[t] = p;
    __syncthreads();
    if (t < LDIM) {
        float sum = 0.f;
        #pragma unroll
        for (int s2 = 0; s2 < 8; s2++) sum += red[s2 * 32 + t];
        out[(size_t)i * LDIM + t] = sum;
    }
}

// ----------------------------------------------------------------
extern "C" void kernel_launch(void* const* d_in, const int* in_sizes, int n_in,
                              void* d_out, int out_size, void* d_ws, size_t ws_size,
                              hipStream_t stream) {
    (void)in_sizes; (void)n_in; (void)out_size; (void)ws_size;
    const float* nf = (const float*)d_in[0];   // [8192][3000]
    const float* G  = (const float*)d_in[1];   // [8192][8192]
    const float* W0 = (const float*)d_in[2];   // [3000][512]
    const float* v0 = (const float*)d_in[3];   // [512]
    const float* v1 = (const float*)d_in[4];   // [512]
    const float* W1 = (const float*)d_in[5];   // [512][30]
    float* out = (float*)d_out;                // [8192][30]

    char* ws = (char*)d_ws;
    size_t off = 0;
    unsigned short* Abf = (unsigned short*)(ws + off); off += (size_t)NN * KP * 2;    // 50,331,648
    unsigned short* W0T = (unsigned short*)(ws + off); off += (size_t)DDIM * KP * 2;  //  3,145,728
    unsigned short* Xbf = (unsigned short*)(ws + off); off += (size_t)NN * DDIM * 2;  //  8,388,608
    float* f0 = (float*)(ws + off); off += NN * 4;     // f0|f1 contiguous (zeroed together)
    float* f1 = (float*)(ws + off); off += NN * 4;

    hipLaunchKernelGGL(k_prep, dim3(NN + 1536 + 1), dim3(384), 0, stream,
                       nf, Abf, W0, W0T, f0);
    hipLaunchKernelGGL(k_gemm, dim3(64, 8), dim3(256), 0, stream,
                       Abf, W0T, v0, v1, Xbf, f0, f1);
    hipLaunchKernelGGL(k_aggregate, dim3(NN), dim3(256), 0, stream,
                       G, Xbf, f0, f1, W1, out);
}